// Round 12
// baseline (510.684 us; speedup 1.0000x reference)
//
#include <hip/hip_runtime.h>
#include <math.h>

// InfoNCE (NT-Xent), N=8192, D=128, fp32 in, scalar fp32 out.
// Unified stacked Gram G=[g1n;g2n]*sqrt(5*log2e), fp8 e4m3, 2N x 128, stored
// FRAGMENT-MAJOR: P[(row>>5)*16 + f][row&31] holds bytes k=8f..8f+7 of row.
// Wrap-strips 0..62 are DUPLICATED after the main array so the triangle
// tile index J = I+dBase+t is affine (no &127 in the hot loop).
// A/B MFMA fragments are single fully-coalesced 512B/wave loads from L2
// (P ~3MB, L2-resident) -> no LDS, no barriers. Lower-triangle tiles only
// (col sums of a tile = row sums of its transpose). Per tile: issue b1 ->
// MFMA(b0) -> issue next b0 -> MFMA(b1) -> exp2 epilogue; every load's
// latency is covered by MFMA or epilogue. b0 half-double-buffered (+16 reg).

constexpr int D = 128;
constexpr float E5 = 148.4131591025766f;   // e^5 (diag self-term)
constexpr int DUPROWS = 63 * 128;          // wrap strips 0..62 duplicated

typedef __attribute__((ext_vector_type(16))) float f32x16;  // 32x32 MFMA acc

__global__ __launch_bounds__(256) void normalize_kernel(
    const float2* __restrict__ h1, const float2* __restrict__ h2,
    unsigned short* __restrict__ P16, float* __restrict__ d12,
    float* __restrict__ rsum, float* __restrict__ out, int N)
{
    const float SC = sqrtf(5.0f * 1.44269504088896340736f);  // sqrt(5*log2e)
    int gid = blockIdx.x * 256 + threadIdx.x;
    if (gid < 2 * N) rsum[gid] = 0.f;
    if (gid == 0) out[0] = 0.f;

    int row  = blockIdx.x * 4 + (threadIdx.x >> 6);
    int lane = threadIdx.x & 63;
    float2 u = h1[(size_t)row * 64 + lane];
    float2 w = h2[(size_t)row * 64 + lane];
    float ss1 = u.x * u.x + u.y * u.y;
    float ss2 = w.x * w.x + w.y * w.y;
    float s12 = u.x * w.x + u.y * w.y;
#pragma unroll
    for (int off = 32; off > 0; off >>= 1) {
        ss1 += __shfl_xor(ss1, off, 64);
        ss2 += __shfl_xor(ss2, off, 64);
        s12 += __shfl_xor(s12, off, 64);
    }
    float n1 = fmaxf(sqrtf(ss1), 1e-12f);
    float n2 = fmaxf(sqrtf(ss2), 1e-12f);
    float c1 = SC / n1, c2 = SC / n2;
    int p1 = __builtin_amdgcn_cvt_pk_fp8_f32(u.x * c1, u.y * c1, 0, false);
    int p2 = __builtin_amdgcn_cvt_pk_fp8_f32(w.x * c2, w.y * c2, 0, false);
    // lane covers bytes k=2*lane,2*lane+1 -> frag f=lane>>2, slot lane&3
    int fi = lane >> 2, li = lane & 3;
    unsigned short v1 = (unsigned short)(p1 & 0xffff);
    unsigned short v2 = (unsigned short)(p2 & 0xffff);
    int r1 = row, r2 = N + row;
    P16[(size_t)(((r1 >> 5) * 16 + fi) * 128) + (r1 & 31) * 4 + li] = v1;
    P16[(size_t)(((r2 >> 5) * 16 + fi) * 128) + (r2 & 31) * 4 + li] = v2;
    if (r1 < DUPROWS) {   // duplicate wrap region (strips 128..190)
        int rd = 16384 + r1;
        P16[(size_t)(((rd >> 5) * 16 + fi) * 128) + (rd & 31) * 4 + li] = v1;
    }
    if (lane == 0) d12[row] = 5.f * s12 / (n1 * n2);
}

// One wave tile = 64x64; block 256 thr (4 waves) covers a 128x128 tile.
// Fragment byte address for (row, f): ((row>>5)*16 + f)*256 + (row&31)*8.
template <int NT>
__device__ __forceinline__ void gram_body(
    const unsigned char* __restrict__ P, float* __restrict__ rsum,
    int I, int dBase, int tx)
{
    const int lane = tx & 63;
    const int l32  = lane & 31, lhi = lane >> 5;
    const int wi   = (tx >> 6) >> 1, wj = (tx >> 6) & 1;
    const int iBase = I * 128;

    // A-fragments: a[st][ks] = frag(row = iBase+wi*64+st*32+l32, f = 2ks+lhi)
    long a[2][8];
#pragma unroll
    for (int st = 0; st < 2; ++st) {
        const unsigned char* xp =
            P + (size_t)I * 16384 + (wi * 2 + st) * 4096 + lhi * 256 + l32 * 8;
#pragma unroll
        for (int ks = 0; ks < 8; ++ks)
            a[st][ks] = *(const long*)(xp + ks * 512);
    }

    float racc0[16], racc1[16];
#pragma unroll
    for (int r = 0; r < 16; ++r) { racc0[r] = 0.f; racc1[r] = 0.f; }
    float cpA[NT], cpB[NT];
#pragma unroll
    for (int t = 0; t < NT; ++t) { cpA[t] = 0.f; cpB[t] = 0.f; }

    const int j0 = wj * 64 + l32;
    const int j1 = j0 + 32;

    // B base for tile t: P + (I+dBase+t)*16384 + wj*2*4096 + lhi*256 + l32*8
    const unsigned char* pb =
        P + (size_t)(I + dBase) * 16384 + wj * 8192 + lhi * 256 + l32 * 8;

    long b0[2][8], b1[8];
#pragma unroll
    for (int ks = 0; ks < 8; ++ks)            // preload b0 of tile 0
        b0[0][ks] = *(const long*)(pb + ks * 512);

#pragma unroll
    for (int t = 0; t < NT; ++t) {
        const int cur = t & 1, nxt = cur ^ 1;

        // issue b1(t); its latency is covered by the b0-MFMA phase below
#pragma unroll
        for (int ks = 0; ks < 8; ++ks)
            b1[ks] = *(const long*)(pb + 4096 + ks * 512);

        f32x16 acc00, acc01, acc10, acc11;
#pragma unroll
        for (int r = 0; r < 16; ++r) {
            acc00[r] = 0.f; acc01[r] = 0.f; acc10[r] = 0.f; acc11[r] = 0.f;
        }

        // b0-phase: 16 MFMAs, two independent acc chains
#pragma unroll
        for (int ks = 0; ks < 8; ++ks) {
            acc00 = __builtin_amdgcn_mfma_f32_32x32x16_fp8_fp8(a[0][ks], b0[cur][ks], acc00, 0, 0, 0);
            acc10 = __builtin_amdgcn_mfma_f32_32x32x16_fp8_fp8(a[1][ks], b0[cur][ks], acc10, 0, 0, 0);
        }

        // issue b0(t+1) into the other buffer; covered by b1-phase + epilogue
        if (t + 1 < NT) {
#pragma unroll
            for (int ks = 0; ks < 8; ++ks)
                b0[nxt][ks] = *(const long*)(pb + 16384 + ks * 512);
        }

        // b1-phase: 16 MFMAs
#pragma unroll
        for (int ks = 0; ks < 8; ++ks) {
            acc01 = __builtin_amdgcn_mfma_f32_32x32x16_fp8_fp8(a[0][ks], b1[ks], acc01, 0, 0, 0);
            acc11 = __builtin_amdgcn_mfma_f32_32x32x16_fp8_fp8(a[1][ks], b1[ks], acc11, 0, 0, 0);
        }

        // epilogue: exp2 + row sums in regs; col partials in regs (deferred)
        float c0 = 0.f, c1 = 0.f;
#pragma unroll
        for (int r = 0; r < 16; ++r) {
            float e00 = __builtin_amdgcn_exp2f(acc00[r]);
            float e01 = __builtin_amdgcn_exp2f(acc01[r]);
            float e10 = __builtin_amdgcn_exp2f(acc10[r]);
            float e11 = __builtin_amdgcn_exp2f(acc11[r]);
            racc0[r] += e00 + e01;
            racc1[r] += e10 + e11;
            c0 += e00 + e10;
            c1 += e01 + e11;
        }
        if ((dBase + t) != 0) { cpA[t] = c0; cpB[t] = c1; }   // skip diag tile
        pb += 16384;
    }

    // flush row sums: butterfly over 32 col-lanes; C row=(r&3)+8*(r>>2)+4*lhi
#pragma unroll
    for (int r = 0; r < 16; ++r) {
        float s0 = racc0[r], s1 = racc1[r];
#pragma unroll
        for (int off = 1; off < 32; off <<= 1) {
            s0 += __shfl_xor(s0, off, 64);
            s1 += __shfl_xor(s1, off, 64);
        }
        if (l32 == 0) {
            int rowm = (r & 3) + 8 * (r >> 2) + 4 * lhi;
            atomicAdd(&rsum[iBase + wi * 64 + rowm], s0);
            atomicAdd(&rsum[iBase + wi * 64 + 32 + rowm], s1);
        }
    }

    // flush col sums (fire-and-forget; nothing waits on these)
#pragma unroll
    for (int t = 0; t < NT; ++t) {
        if ((dBase + t) == 0) continue;
        float c0 = cpA[t], c1 = cpB[t];
        c0 += __shfl_xor(c0, 32, 64);   // merge lhi halves
        c1 += __shfl_xor(c1, 32, 64);
        if (lane < 32) {
            int jb = ((I + dBase + t) & 127) * 128;   // wrap only here
            atomicAdd(&rsum[jb + j0], c0);
            atomicAdd(&rsum[jb + j1], c1);
        }
    }
}

// Strips of 128 rows over 2N=16384 -> 128 strips. Tiles (I, I+d) with the
// wrap region duplicated: y<16 -> d=4y..4y+3 (NT=4); y==16, I<64 -> d=64.
__global__ __launch_bounds__(256, 3) void gram_mfma_kernel(
    const unsigned char* __restrict__ P, float* __restrict__ rsum, int N)
{
    const int I = blockIdx.x;
    if (blockIdx.y < 16) {
        gram_body<4>(P, rsum, I, (int)blockIdx.y * 4, threadIdx.x);
    } else if (I < 64) {
        gram_body<1>(P, rsum, I, 64, threadIdx.x);
    }
}

// loss_i = 0.5*(log(rsum[i]-e5) + log(rsum[N+i]-e5)) - d12 ; out = mean
__global__ __launch_bounds__(256) void loss_reduce_kernel(
    const float* __restrict__ rsum, const float* __restrict__ d12,
    float* __restrict__ out, int N)
{
    __shared__ float sm[256];
    float s = 0.f;
    for (int i = blockIdx.x * 256 + threadIdx.x; i < N; i += gridDim.x * 256) {
        float neg1 = rsum[i] - E5;
        float neg2 = rsum[N + i] - E5;
        s += 0.5f * (logf(neg1) + logf(neg2)) - d12[i];
    }
    sm[threadIdx.x] = s;
    __syncthreads();
    for (int w = 128; w > 0; w >>= 1) {
        if (threadIdx.x < w) sm[threadIdx.x] += sm[threadIdx.x + w];
        __syncthreads();
    }
    if (threadIdx.x == 0) atomicAdd(out, sm[0] / (float)N);
}

extern "C" void kernel_launch(void* const* d_in, const int* in_sizes, int n_in,
                              void* d_out, int out_size, void* d_ws, size_t ws_size,
                              hipStream_t stream) {
    const float* h1 = (const float*)d_in[0];
    const float* h2 = (const float*)d_in[1];
    const int N = in_sizes[0] / D;   // 8192

    unsigned char* P = (unsigned char*)d_ws;        // frag-major fp8 + dup (~3.1MB)
    float* rsum = (float*)(P + (size_t)4 * 1024 * 1024);   // 2N
    float* d12  = rsum + 2 * N;                            // N
    float* out  = (float*)d_out;

    normalize_kernel<<<N / 4, 256, 0, stream>>>(
        (const float2*)h1, (const float2*)h2,
        (unsigned short*)P, d12, rsum, out, N);

    dim3 grid(128, 17, 1);
    gram_mfma_kernel<<<grid, 256, 0, stream>>>(P, rsum, N);

    loss_reduce_kernel<<<32, 256, 0, stream>>>(rsum, d12, out, N);
}

// Round 13
// 107.112 us; speedup vs baseline: 4.7678x; 4.7678x over previous
//
#include <hip/hip_runtime.h>
#include <math.h>

// InfoNCE (NT-Xent), N=8192, D=128, fp32 in, scalar fp32 out.
// Unified stacked Gram G=[g1n;g2n]*sqrt(5*log2e), fp8 e4m3, 2N x 128, stored
// FRAGMENT-MAJOR: P[(row>>5)*16 + f][row&31] holds bytes k=8f..8f+7 of row.
// A/B MFMA fragments are fully-coalesced 512B/wave loads from L2 (P = 2MB,
// L2-resident) -> no LDS, no barriers. Lower-triangle tiles only (col sums
// of a tile = row sums of its transpose). MFMA = MX-scaled 32x32x64 f8f6f4
// with unit scales (0x7F e8m0), fmt fp8-e4m3: 8 MFMAs/tile at 2x fp8 rate,
// register-identical to the 32x32x16 version (r10). neg_i = rsum[i]-E5.

constexpr int D = 128;
constexpr float E5 = 148.4131591025766f;   // e^5 (diag self-term)

typedef __attribute__((ext_vector_type(16))) float f32x16;  // 32x32 MFMA acc
typedef __attribute__((ext_vector_type(8)))  int   v8i;     // 32-byte operand
typedef __attribute__((ext_vector_type(4)))  long  v4l;

__global__ __launch_bounds__(256) void normalize_kernel(
    const float2* __restrict__ h1, const float2* __restrict__ h2,
    unsigned short* __restrict__ P16, float* __restrict__ d12,
    float* __restrict__ rsum, float* __restrict__ out, int N)
{
    const float SC = sqrtf(5.0f * 1.44269504088896340736f);  // sqrt(5*log2e)
    int gid = blockIdx.x * 256 + threadIdx.x;
    if (gid < 2 * N) rsum[gid] = 0.f;
    if (gid == 0) out[0] = 0.f;

    int row  = blockIdx.x * 4 + (threadIdx.x >> 6);
    int lane = threadIdx.x & 63;
    float2 u = h1[(size_t)row * 64 + lane];
    float2 w = h2[(size_t)row * 64 + lane];
    float ss1 = u.x * u.x + u.y * u.y;
    float ss2 = w.x * w.x + w.y * w.y;
    float s12 = u.x * w.x + u.y * w.y;
#pragma unroll
    for (int off = 32; off > 0; off >>= 1) {
        ss1 += __shfl_xor(ss1, off, 64);
        ss2 += __shfl_xor(ss2, off, 64);
        s12 += __shfl_xor(s12, off, 64);
    }
    float n1 = fmaxf(sqrtf(ss1), 1e-12f);
    float n2 = fmaxf(sqrtf(ss2), 1e-12f);
    float c1 = SC / n1, c2 = SC / n2;
    int p1 = __builtin_amdgcn_cvt_pk_fp8_f32(u.x * c1, u.y * c1, 0, false);
    int p2 = __builtin_amdgcn_cvt_pk_fp8_f32(w.x * c2, w.y * c2, 0, false);
    // lane covers bytes k=2*lane,2*lane+1 -> frag f=lane>>2, slot lane&3
    int r1 = row, r2 = N + row;
    int fi = lane >> 2, li = lane & 3;
    P16[(size_t)(((r1 >> 5) * 16 + fi) * 128) + (r1 & 31) * 4 + li] =
        (unsigned short)(p1 & 0xffff);
    P16[(size_t)(((r2 >> 5) * 16 + fi) * 128) + (r2 & 31) * 4 + li] =
        (unsigned short)(p2 & 0xffff);
    if (lane == 0) d12[row] = 5.f * s12 / (n1 * n2);
}

// Load a 32-byte K=64 operand: lane holds k=(lhi*32..+31) of row l32 ->
// 4 frags at stride 256B, 8B each. Stays in 8 VGPRs (v4l -> v8i bitcast).
__device__ __forceinline__ v8i load_op(const unsigned char* p) {
    v4l t;
    t[0] = *(const long*)(p);
    t[1] = *(const long*)(p + 256);
    t[2] = *(const long*)(p + 512);
    t[3] = *(const long*)(p + 768);
    return __builtin_bit_cast(v8i, t);
}

// Strips of 128 rows over 2N=16384 -> 128 strips. Tiles (I,(I+d)&127):
// y<16 -> d=4y..4y+3 (nT=4); y==16, I<64 -> d=64 (nT=1). Each unordered
// strip pair exactly once. Block 256 thr (4 waves), wave tile 64x64.
// Strip base: P + strip*16384; col-half (+4096); frag f at +f*256; row l32*8.
// Operand for kchunk kc, lane half lhi: frags kc*8+lhi*4 .. +3.
__global__ __launch_bounds__(256, 2) void gram_mfma_kernel(
    const unsigned char* __restrict__ P, float* __restrict__ rsum, int N)
{
    const int I = blockIdx.x;
    int nT = 4, dBase = 0;
    if (blockIdx.y < 16) { dBase = blockIdx.y * 4; }
    else if (I < 64)     { nT = 1; dBase = 64; }
    else return;

    const int tx   = threadIdx.x;
    const int lane = tx & 63;
    const int l32  = lane & 31, lhi = lane >> 5;
    const int wi   = (tx >> 6) >> 1, wj = (tx >> 6) & 1;
    const int iBase = I * 128;
    const int fOff = lhi * 1024;   // lhi*4 frags * 256B

    // A-operands: a[st][kc], rows iBase+wi*64+st*32+l32, k = kc*64+lhi*32..+31
    v8i a[2][2];
#pragma unroll
    for (int st = 0; st < 2; ++st) {
        const unsigned char* xp =
            P + (size_t)(I * 4 + wi * 2 + st) * 4096 + fOff + l32 * 8;
#pragma unroll
        for (int kc = 0; kc < 2; ++kc)
            a[st][kc] = load_op(xp + kc * 2048);
    }

    float racc0[16], racc1[16];
#pragma unroll
    for (int r = 0; r < 16; ++r) { racc0[r] = 0.f; racc1[r] = 0.f; }
    float cpA[4] = {0.f, 0.f, 0.f, 0.f};
    float cpB[4] = {0.f, 0.f, 0.f, 0.f};

    const int j0 = wj * 64 + l32;
    const int j1 = j0 + 32;

    for (int t = 0; t < nT; ++t) {
        const int J = (I + dBase + t) & 127;
        const unsigned char* pb =
            P + (size_t)(J * 4 + wj * 2) * 4096 + fOff + l32 * 8;

        v8i b0[2], b1[2];
#pragma unroll
        for (int kc = 0; kc < 2; ++kc) {
            b0[kc] = load_op(pb + kc * 2048);
            b1[kc] = load_op(pb + 4096 + kc * 2048);
        }

        f32x16 acc00, acc01, acc10, acc11;
#pragma unroll
        for (int r = 0; r < 16; ++r) {
            acc00[r] = 0.f; acc01[r] = 0.f; acc10[r] = 0.f; acc11[r] = 0.f;
        }

#pragma unroll
        for (int kc = 0; kc < 2; ++kc) {
            acc00 = __builtin_amdgcn_mfma_scale_f32_32x32x64_f8f6f4(
                a[0][kc], b0[kc], acc00, 0, 0, 0, 127, 0, 127);
            acc10 = __builtin_amdgcn_mfma_scale_f32_32x32x64_f8f6f4(
                a[1][kc], b0[kc], acc10, 0, 0, 0, 127, 0, 127);
            acc01 = __builtin_amdgcn_mfma_scale_f32_32x32x64_f8f6f4(
                a[0][kc], b1[kc], acc01, 0, 0, 0, 127, 0, 127);
            acc11 = __builtin_amdgcn_mfma_scale_f32_32x32x64_f8f6f4(
                a[1][kc], b1[kc], acc11, 0, 0, 0, 127, 0, 127);
        }

        // epilogue: exp2 + row sums in regs; col partials in regs (deferred)
        float c0 = 0.f, c1 = 0.f;
#pragma unroll
        for (int r = 0; r < 16; ++r) {
            float e00 = __builtin_amdgcn_exp2f(acc00[r]);
            float e01 = __builtin_amdgcn_exp2f(acc01[r]);
            float e10 = __builtin_amdgcn_exp2f(acc10[r]);
            float e11 = __builtin_amdgcn_exp2f(acc11[r]);
            racc0[r] += e00 + e01;
            racc1[r] += e10 + e11;
            c0 += e00 + e10;
            c1 += e01 + e11;
        }
        if ((dBase + t) != 0) { cpA[t] = c0; cpB[t] = c1; }   // skip diag tile
    }

    // flush row sums: butterfly over 32 col-lanes; C row=(r&3)+8*(r>>2)+4*lhi
#pragma unroll
    for (int r = 0; r < 16; ++r) {
        float s0 = racc0[r], s1 = racc1[r];
#pragma unroll
        for (int off = 1; off < 32; off <<= 1) {
            s0 += __shfl_xor(s0, off, 64);
            s1 += __shfl_xor(s1, off, 64);
        }
        if (l32 == 0) {
            int rowm = (r & 3) + 8 * (r >> 2) + 4 * lhi;
            atomicAdd(&rsum[iBase + wi * 64 + rowm], s0);
            atomicAdd(&rsum[iBase + wi * 64 + 32 + rowm], s1);
        }
    }

    // flush col sums (fire-and-forget; nothing waits on these)
#pragma unroll
    for (int t = 0; t < 4; ++t) {
        if (t >= nT) break;
        if ((dBase + t) == 0) continue;
        float c0 = cpA[t], c1 = cpB[t];
        c0 += __shfl_xor(c0, 32, 64);   // merge lhi halves
        c1 += __shfl_xor(c1, 32, 64);
        if (lane < 32) {
            int jb = ((I + dBase + t) & 127) * 128;
            atomicAdd(&rsum[jb + j0], c0);
            atomicAdd(&rsum[jb + j1], c1);
        }
    }
}

// loss_i = 0.5*(log(rsum[i]-e5) + log(rsum[N+i]-e5)) - d12 ; out = mean
__global__ __launch_bounds__(256) void loss_reduce_kernel(
    const float* __restrict__ rsum, const float* __restrict__ d12,
    float* __restrict__ out, int N)
{
    __shared__ float sm[256];
    float s = 0.f;
    for (int i = blockIdx.x * 256 + threadIdx.x; i < N; i += gridDim.x * 256) {
        float neg1 = rsum[i] - E5;
        float neg2 = rsum[N + i] - E5;
        s += 0.5f * (logf(neg1) + logf(neg2)) - d12[i];
    }
    sm[threadIdx.x] = s;
    __syncthreads();
    for (int w = 128; w > 0; w >>= 1) {
        if (threadIdx.x < w) sm[threadIdx.x] += sm[threadIdx.x + w];
        __syncthreads();
    }
    if (threadIdx.x == 0) atomicAdd(out, sm[0] / (float)N);
}

extern "C" void kernel_launch(void* const* d_in, const int* in_sizes, int n_in,
                              void* d_out, int out_size, void* d_ws, size_t ws_size,
                              hipStream_t stream) {
    const float* h1 = (const float*)d_in[0];
    const float* h2 = (const float*)d_in[1];
    const int N = in_sizes[0] / D;   // 8192

    unsigned char* P = (unsigned char*)d_ws;                // 2N x 128 fp8, frag-major
    float* rsum = (float*)(P + (size_t)2 * N * D);          // 2N
    float* d12  = rsum + 2 * N;                             // N
    float* out  = (float*)d_out;

    normalize_kernel<<<N / 4, 256, 0, stream>>>(
        (const float2*)h1, (const float2*)h2,
        (unsigned short*)P, d12, rsum, out, N);

    dim3 grid(128, 17, 1);
    gram_mfma_kernel<<<grid, 256, 0, stream>>>(P, rsum, N);

    loss_reduce_kernel<<<32, 256, 0, stream>>>(rsum, d12, out, N);
}